// Round 7
// baseline (147.507 us; speedup 1.0000x reference)
//
#include <hip/hip_runtime.h>

#define NQ      10
#define NLAYERS 4
#define D_IN    784
#define BLOCK   256   // 4 waves per workgroup, ONE state per wave, amp-pair pk packing.
// R19: occupancy probe. R18 landed 82us @ VALUBusy 69 / occupancy 34.5 with VGPR=64 and
// 8 waves/SIMD supplied by the grid -> residency, not issue, is the suspect. Cross-round
// pattern: occupancy tracks the waves_per_eu MINIMUM ((8,8)->56%, (4,8)->36%, (2,8)->35%)
// not reported VGPR => on gfx950's unified VGPR/AGPR file the allocator parks overflow in
// AGPRs (not shown in VGPR_Count); total ~128/wave caps 4 waves/SIMD. Fix attempt: (6,8)
// = ~85-reg total budget. R18's lean kernel needs ~60-80 live regs (vs R13-era ~110), so
// this should fit. 6 waves/SIMD resident = 2x current.
// Outcomes: clean (WRITE ~320KB) + busy>=78 -> dur ~66-72us. Spill (WRITE >>1MB) ->
// true need >85 regs, diet registers next. Flat+clean -> dependency chain is the floor.
// R18 (kept): layer factorization Rot = D_omega * RY * D_phi; diagonals as lane-phase
// sincos x 16-entry LDS table; last D_omega skipped; embedding = product-state init;
// ring CNOT(9,0) folded into D_phi signs / ry0_fused / measurement masks.
// Tripwire: WRITE_SIZE ~0.3 MB. absmax must stay ~0.004.
// LOCKED: reductions use plain __shfl_xor only (R8 DPP reductions diverged across graph
// replays). DPP confined to full-exec lane exchanges (stable since R4).

// Amplitude index i (10 bits): lane bits 9..4 (q0..q5 = lane&32..lane&1),
// array-index bits 3..1 (q6,q7,q8 = a&4,a&2,a&1), component bit 0 (q9 = f2 comp).

typedef __attribute__((ext_vector_type(2))) float f2;

__device__ __forceinline__ f2 sp(float v) { f2 r; r.x = v; r.y = v; return r; }
__device__ __forceinline__ f2 swapc(f2 v) { return __builtin_shufflevector(v, v, 1, 0); }

// ---- lane exchange: xor LB, VALU pipe where possible ----
template<int LB>
__device__ __forceinline__ float lx(float v) {
    if constexpr (LB == 1) {        // quad_perm [1,0,3,2]
        return __int_as_float(__builtin_amdgcn_update_dpp(
            0, __float_as_int(v), 0xB1, 0xF, 0xF, false));
    } else if constexpr (LB == 2) { // quad_perm [2,3,0,1]
        return __int_as_float(__builtin_amdgcn_update_dpp(
            0, __float_as_int(v), 0x4E, 0xF, 0xF, false));
    } else if constexpr (LB == 8) { // row_ror:8 within 16 == xor 8 (VALU)
        return __int_as_float(__builtin_amdgcn_update_dpp(
            0, __float_as_int(v), 0x128, 0xF, 0xF, false));
    } else {
        return __shfl_xor(v, LB, 64);   // LB==4: DS pipe (no VALU equivalent)
    }
}

template<int LB>
__device__ __forceinline__ f2 lx2(f2 v) {
    f2 r; r.x = lx<LB>(v.x); r.y = lx<LB>(v.y); return r;
}

// ---- permlane pair swap (VALU pipe) ----
template<int HALF>
__device__ __forceinline__ void plswap(f2 &d, f2 &s) {
    if constexpr (HALF == 32) {
        auto rx = __builtin_amdgcn_permlane32_swap(__float_as_int(d.x), __float_as_int(s.x), false, false);
        auto ry = __builtin_amdgcn_permlane32_swap(__float_as_int(d.y), __float_as_int(s.y), false, false);
        d.x = __int_as_float(rx[0]); s.x = __int_as_float(rx[1]);
        d.y = __int_as_float(ry[0]); s.y = __int_as_float(ry[1]);
    } else {
        auto rx = __builtin_amdgcn_permlane16_swap(__float_as_int(d.x), __float_as_int(s.x), false, false);
        auto ry = __builtin_amdgcn_permlane16_swap(__float_as_int(d.y), __float_as_int(s.y), false, false);
        d.x = __int_as_float(rx[0]); s.x = __int_as_float(rx[1]);
        d.y = __int_as_float(ry[0]); s.y = __int_as_float(ry[1]);
    }
}

// ---- real RY on lane bit 32/16 via permlane pair-processing ----
template<int HALF>
__device__ __forceinline__ void ry_pl(f2 (&re)[8], f2 (&im)[8], float c, float s) {
#pragma unroll
    for (int a = 0; a < 8; a += 2) {
        f2 ur = re[a], vr = re[a + 1], ui = im[a], vi = im[a + 1];
        plswap<HALF>(ur, vr); plswap<HALF>(ui, vi);
        f2 nur = sp(c)*ur - sp(s)*vr;   f2 nui = sp(c)*ui - sp(s)*vi;
        f2 nvr = sp(s)*ur + sp(c)*vr;   f2 nvi = sp(s)*ui + sp(c)*vi;
        plswap<HALF>(nur, nvr); plswap<HALF>(nui, nvi);
        re[a] = nur; re[a + 1] = nvr; im[a] = nui; im[a + 1] = nvi;
    }
}

// ---- real RY on q0 (lane bit 32) with pending CNOT(ctrl=comp, tgt=bit32) consumed.
// After plswap every lane holds (u=amp(b0=0), v=amp(b0=1)); comp1 sees the pair
// pre-swapped by the CNOT -> coefficient-packed f2 constants. ----
__device__ __forceinline__ void ry0_fused(f2 (&re)[8], f2 (&im)[8], float c, float s) {
    f2 K1, K2, K3, K4;
    K1.x =  c; K1.y = -s;   K2.x = -s; K2.y =  c;
    K3.x =  s; K3.y =  c;   K4.x =  c; K4.y =  s;
#pragma unroll
    for (int a = 0; a < 8; a += 2) {
        f2 ur = re[a], vr = re[a + 1], ui = im[a], vi = im[a + 1];
        plswap<32>(ur, vr); plswap<32>(ui, vi);
        f2 nur = K1*ur + K2*vr;   f2 nui = K1*ui + K2*vi;
        f2 nvr = K3*ur + K4*vr;   f2 nvi = K3*ui + K4*vi;
        plswap<32>(nur, nvr); plswap<32>(nui, nvi);
        re[a] = nur; re[a + 1] = nvr; im[a] = nui; im[a + 1] = nvi;
    }
}

// ---- real RY on lane bit LB (8,4,2,1): exchange + 4 pk per reg ----
template<int LB>
__device__ __forceinline__ void ry_lane(f2 (&re)[8], f2 (&im)[8], int lane, float c, float s) {
    const float o = (lane & LB) ? s : -s;   // lo: u' = c*u - s*v ; hi: v' = c*v + s*u
#pragma unroll
    for (int a = 0; a < 8; a++) {
        f2 ore = lx2<LB>(re[a]);
        f2 oim = lx2<LB>(im[a]);
        re[a] = sp(c)*re[a] + sp(o)*ore;
        im[a] = sp(c)*im[a] + sp(o)*oim;
    }
}

// ---- real RY on array-index bit MB (4,2,1): 8 pk per pair ----
template<int MB>
__device__ __forceinline__ void ry_reg(f2 (&re)[8], f2 (&im)[8], float c, float s) {
#pragma unroll
    for (int a = 0; a < 8; a++) {
        if (!(a & MB)) {
            const int a1 = a | MB;
            f2 r0 = re[a], r1 = re[a1], i0 = im[a], i1 = im[a1];
            re[a]  = sp(c)*r0 - sp(s)*r1;   re[a1] = sp(s)*r0 + sp(c)*r1;
            im[a]  = sp(c)*i0 - sp(s)*i1;   im[a1] = sp(s)*i0 + sp(c)*i1;
        }
    }
}

// ---- real RY on the component bit (q9): swapc + 4 pk per reg ----
__device__ __forceinline__ void ry_comp(f2 (&re)[8], f2 (&im)[8], float c, float s) {
    f2 Ks; Ks.x = -s; Ks.y = s;
#pragma unroll
    for (int a = 0; a < 8; a++) {
        f2 sre = swapc(re[a]), sim = swapc(im[a]);
        re[a] = sp(c)*re[a] + Ks*sre;
        im[a] = sp(c)*im[a] + Ks*sim;
    }
}

// ---- diagonal apply: per-amp factor = e^{i*lane_phase} * e^{i*reg_phase[a]}.
// XOR0: pending CNOT(q9->q0) folded in -> phi0 lane-term sign flips on component. ----
template<bool XOR0>
__device__ __forceinline__ void diag_apply(f2 (&re)[8], f2 (&im)[8], int lane,
                                           const float* lz, const f2* DC, const f2* DS) {
    float lp = 0.f;
    lp += (lane & 16) ? lz[1] : -lz[1];
    lp += (lane &  8) ? lz[2] : -lz[2];
    lp += (lane &  4) ? lz[3] : -lz[3];
    lp += (lane &  2) ? lz[4] : -lz[4];
    lp += (lane &  1) ? lz[5] : -lz[5];
    const float t0 = (lane & 32) ? lz[0] : -lz[0];
    f2 cl, sl;
    if constexpr (XOR0) {
        float sa, ca, sb, cb;
        sincosf(lp + t0, &sa, &ca);
        sincosf(lp - t0, &sb, &cb);
        cl.x = ca; cl.y = cb; sl.x = sa; sl.y = sb;
    } else {
        float sa, ca;
        sincosf(lp + t0, &sa, &ca);
        cl = sp(ca); sl = sp(sa);
    }
#pragma unroll
    for (int a = 0; a < 8; a++) {
        f2 cr = cl*DC[a] - sl*DS[a];      // combined complex coefficient
        f2 ci = cl*DS[a] + sl*DC[a];
        f2 nr = cr*re[a] - ci*im[a];
        f2 ni = cr*im[a] + ci*re[a];
        re[a] = nr; im[a] = ni;
    }
}

__device__ __forceinline__ void swapf2(f2 &a, f2 &b) { f2 t = a; a = b; b = t; }

// ---- CNOT ring: Gray bpermute (q0..q5 chain), (5,6) cndmask, renames, (8,9) comp swap.
// (9,0) NOT applied: folded into next layer's D_phi/ry0_fused or measurement signs. ----
__device__ __forceinline__ void ring(f2 (&re)[8], f2 (&im)[8], int lane, int bidx) {
#pragma unroll
    for (int a = 0; a < 8; a++) {
        re[a].x = __int_as_float(__builtin_amdgcn_ds_bpermute(bidx, __float_as_int(re[a].x)));
        re[a].y = __int_as_float(__builtin_amdgcn_ds_bpermute(bidx, __float_as_int(re[a].y)));
        im[a].x = __int_as_float(__builtin_amdgcn_ds_bpermute(bidx, __float_as_int(im[a].x)));
        im[a].y = __int_as_float(__builtin_amdgcn_ds_bpermute(bidx, __float_as_int(im[a].y)));
    }
    const bool ctl = (lane & 1) != 0;      // (5,6): ctrl lane bit0, tgt array bit 4
#pragma unroll
    for (int a = 0; a < 4; a++) {
        f2 A0 = re[a], A1 = re[a + 4], B0 = im[a], B1 = im[a + 4];
        f2 n0, n1, m0, m1;
        n0.x = ctl ? A1.x : A0.x;  n0.y = ctl ? A1.y : A0.y;
        n1.x = ctl ? A0.x : A1.x;  n1.y = ctl ? A0.y : A1.y;
        m0.x = ctl ? B1.x : B0.x;  m0.y = ctl ? B1.y : B0.y;
        m1.x = ctl ? B0.x : B1.x;  m1.y = ctl ? B0.y : B1.y;
        re[a] = n0; re[a + 4] = n1; im[a] = m0; im[a + 4] = m1;
    }
    // (6,7): ctrl array bit 4, tgt bit 2: free renames
    swapf2(re[4], re[6]); swapf2(re[5], re[7]); swapf2(im[4], im[6]); swapf2(im[5], im[7]);
    // (7,8): ctrl array bit 2, tgt bit 1
    swapf2(re[2], re[3]); swapf2(re[6], re[7]); swapf2(im[2], im[3]); swapf2(im[6], im[7]);
    // (8,9): ctrl array bit 1, tgt component
#pragma unroll
    for (int a = 1; a < 8; a += 2) { re[a] = swapc(re[a]); im[a] = swapc(im[a]); }
}

__global__ __launch_bounds__(BLOCK)
__attribute__((amdgpu_waves_per_eu(6, 8)))
void qnet_kernel(
    const float* __restrict__ x,
    const float* __restrict__ Wp,
    const float* __restrict__ bp,
    const float* __restrict__ qw,
    const float* __restrict__ Wo,
    const float* __restrict__ bo,
    float* __restrict__ out, int B)
{
    // Per-WG tables:
    __shared__ float ryt[NLAYERS * NQ * 2];        // (l*10+q)*2: cos(th/2), sin(th/2)
    __shared__ float lzt[NLAYERS * 2 * 6];         // (l*2+t)*6+q: half-angles q0..q5 (t:0=phi,1=omega)
    __shared__ __align__(8) f2 dct[NLAYERS * 2 * 8];  // (l*2+t)*8+a: reg-diag cos (comp-packed)
    __shared__ __align__(8) f2 dst[NLAYERS * 2 * 8];  // reg-diag sin

    const int tid  = threadIdx.x;
    const int lane = tid & 63;
    const int s    = blockIdx.x * (BLOCK / 64) + (tid >> 6);   // one state per wave

    if (tid < NLAYERS * NQ) {                      // 40 threads: RY pairs + lane half-angles
        const int l = tid / NQ, q = tid % NQ;
        float th = qw[tid * 3 + 1];
        float sc, cc; sincosf(0.5f * th, &sc, &cc);
        ryt[tid * 2] = cc; ryt[tid * 2 + 1] = sc;
        if (q < 6) {
            lzt[(l * 2 + 0) * 6 + q] = 0.5f * qw[tid * 3 + 0];   // phi
            lzt[(l * 2 + 1) * 6 + q] = 0.5f * qw[tid * 3 + 2];   // omega
        }
    }
    if (tid >= 64 && tid < 128) {                  // 64 threads: reg-diag tables
        const int idx = tid - 64;
        const int l = idx >> 4, t = (idx >> 3) & 1, a = idx & 7;
        const float* ql = qw + (size_t)l * NQ * 3;
        const int off = t ? 2 : 0;
        const float p6 = 0.5f * ql[6 * 3 + off], p7 = 0.5f * ql[7 * 3 + off];
        const float p8 = 0.5f * ql[8 * 3 + off], p9 = 0.5f * ql[9 * 3 + off];
        const float base = ((a & 4) ? p6 : -p6) + ((a & 2) ? p7 : -p7) + ((a & 1) ? p8 : -p8);
        float s0, c0, s1, c1;
        sincosf(base - p9, &s0, &c0);              // comp 0: q9 bit = 0
        sincosf(base + p9, &s1, &c1);              // comp 1: q9 bit = 1
        f2 dc; dc.x = c0; dc.y = c1;
        f2 ds; ds.x = s0; ds.y = s1;
        dct[(l * 2 + t) * 8 + a] = dc;
        dst[(l * 2 + t) * 8 + a] = ds;
    }
    __syncthreads();
    if (s >= B) return;

    // ---- projection (float4: 784 = 3*256 + 16) ----
    float acc[NQ];
#pragma unroll
    for (int q = 0; q < NQ; q++) acc[q] = 0.f;
    const float* xr = x + (size_t)s * D_IN;
#pragma unroll
    for (int it = 0; it < 3; it++) {
        const int d = (it * 64 + lane) * 4;
        float4 xv = *(const float4*)(xr + d);
#pragma unroll
        for (int q = 0; q < NQ; q++) {
            float4 wv = *(const float4*)(Wp + q * D_IN + d);
            acc[q] += xv.x * wv.x + xv.y * wv.y + xv.z * wv.z + xv.w * wv.w;
        }
    }
    if (lane < 4) {                                // tail 768..783
        const int d = (192 + lane) * 4;
        float4 xv = *(const float4*)(xr + d);
#pragma unroll
        for (int q = 0; q < NQ; q++) {
            float4 wv = *(const float4*)(Wp + q * D_IN + d);
            acc[q] += xv.x * wv.x + xv.y * wv.y + xv.z * wv.z + xv.w * wv.w;
        }
    }
#pragma unroll
    for (int q = 0; q < NQ; q++) {
#pragma unroll
        for (int o = 1; o < 64; o <<= 1) acc[q] += __shfl_xor(acc[q], o, 64);
    }
    float myc = 1.f, mys = 0.f;
    if (lane < NQ) {
        float h = tanhf(acc[lane] + bp[lane]);
        sincosf(0.5f * h, &mys, &myc);
    }

    // ---- embedding: direct product-state init (all-real, separable) ----
    f2 re[8], im[8];
    float lf = 1.f;
    {
        float cq, sq;
#define SEL(Q, MASK) cq = __shfl(myc, Q, 64); sq = __shfl(mys, Q, 64); \
                     lf *= (lane & MASK) ? sq : cq;
        SEL(0, 32) SEL(1, 16) SEL(2, 8) SEL(3, 4) SEL(4, 2) SEL(5, 1)
#undef SEL
        const float c6 = __shfl(myc, 6, 64), s6 = __shfl(mys, 6, 64);
        const float c7 = __shfl(myc, 7, 64), s7 = __shfl(mys, 7, 64);
        const float c8 = __shfl(myc, 8, 64), s8 = __shfl(mys, 8, 64);
        const float c9 = __shfl(myc, 9, 64), s9 = __shfl(mys, 9, 64);
#pragma unroll
        for (int a = 0; a < 8; a++) {
            float t = ((a & 4) ? s6 : c6) * ((a & 2) ? s7 : c7) * ((a & 1) ? s8 : c8) * lf;
            re[a].x = t * c9; re[a].y = t * s9;
            im[a] = sp(0.f);
        }
    }

    const int bidx = (lane ^ (lane >> 1)) << 2;    // Gray pull for lane CNOT chain

    // ---- layer 0: D_phi, 10 RYs, D_omega, ring ----
    {
        const float* rl = ryt;
        diag_apply<false>(re, im, lane, lzt, dct, dst);                    // D_phi(0)
        ry_pl<32>(re, im, rl[0], rl[1]);
        ry_pl<16>(re, im, rl[2], rl[3]);
        ry_lane<8>(re, im, lane, rl[4], rl[5]);
        ry_lane<4>(re, im, lane, rl[6], rl[7]);
        ry_lane<2>(re, im, lane, rl[8], rl[9]);
        ry_lane<1>(re, im, lane, rl[10], rl[11]);
        ry_reg<4>(re, im, rl[12], rl[13]);
        ry_reg<2>(re, im, rl[14], rl[15]);
        ry_reg<1>(re, im, rl[16], rl[17]);
        ry_comp(re, im, rl[18], rl[19]);
        diag_apply<false>(re, im, lane, lzt + 6, dct + 8, dst + 8);        // D_omega(0)
        ring(re, im, lane, bidx);                  // leaves (9,0) pending
    }

    // ---- layers 1..3 ----
    for (int l = 1; l < NLAYERS; l++) {
        const float* rl = ryt + l * NQ * 2;
        diag_apply<true>(re, im, lane, lzt + (l * 2) * 6,
                         dct + (l * 2) * 8, dst + (l * 2) * 8);            // D'_phi (C folded)
        ry0_fused(re, im, rl[0], rl[1]);           // consumes pending C
        ry_pl<16>(re, im, rl[2], rl[3]);
        ry_lane<8>(re, im, lane, rl[4], rl[5]);
        ry_lane<4>(re, im, lane, rl[6], rl[7]);
        ry_lane<2>(re, im, lane, rl[8], rl[9]);
        ry_lane<1>(re, im, lane, rl[10], rl[11]);
        ry_reg<4>(re, im, rl[12], rl[13]);
        ry_reg<2>(re, im, rl[14], rl[15]);
        ry_reg<1>(re, im, rl[16], rl[17]);
        ry_comp(re, im, rl[18], rl[19]);
        if (l < NLAYERS - 1)                       // last D_omega skipped (|amp|^2 invariant)
            diag_apply<false>(re, im, lane, lzt + (l * 2 + 1) * 6,
                              dct + (l * 2 + 1) * 8, dst + (l * 2 + 1) * 8);
        ring(re, im, lane, bidx);                  // (9,0) pending again
    }
    // Final pending (9,0) CNOT folded into measurement sign masks below.

    // ---- measurement: Z expectation per qubit ----
    f2 S2 = {0.f, 0.f}, z62 = {0.f, 0.f}, z72 = {0.f, 0.f}, z82 = {0.f, 0.f};
#pragma unroll
    for (int a = 0; a < 8; a++) {
        f2 p = re[a] * re[a] + im[a] * im[a];
        S2 += p;
        if (a & 4) z62 -= p; else z62 += p;
        if (a & 2) z72 -= p; else z72 += p;
        if (a & 1) z82 -= p; else z82 += p;
    }
    const float Ssum = S2.x + S2.y;
    const float Sdif = S2.x - S2.y;
    float zq[NQ];
    zq[0] = (lane & 32) ? -Sdif : Sdif;   // q0: lane bit32 XOR component (folded CNOT)
    zq[1] = (lane & 16) ? -Ssum : Ssum;
    zq[2] = (lane &  8) ? -Ssum : Ssum;
    zq[3] = (lane &  4) ? -Ssum : Ssum;
    zq[4] = (lane &  2) ? -Ssum : Ssum;
    zq[5] = (lane &  1) ? -Ssum : Ssum;
    zq[6] = z62.x + z62.y;
    zq[7] = z72.x + z72.y;
    zq[8] = z82.x + z82.y;
    zq[9] = Sdif;                          // q9: component bit (untouched by folded CNOT)
#pragma unroll
    for (int q = 0; q < NQ; q++) {
#pragma unroll
        for (int o = 1; o < 64; o <<= 1) zq[q] += __shfl_xor(zq[q], o, 64);
    }

    // ---- output projection: out = zq @ Wo^T + bo ----
    if (lane < NQ) {
        const float* wrow = Wo + lane * NQ;
        float o0 = bo[lane];
#pragma unroll
        for (int q = 0; q < NQ; q++) o0 += zq[q] * wrow[q];
        out[(size_t)s * NQ + lane] = o0;
    }
}

extern "C" void kernel_launch(void* const* d_in, const int* in_sizes, int n_in,
                              void* d_out, int out_size, void* d_ws, size_t ws_size,
                              hipStream_t stream) {
    const float* x  = (const float*)d_in[0];
    const float* Wp = (const float*)d_in[1];
    const float* bp = (const float*)d_in[2];
    const float* qw = (const float*)d_in[3];
    const float* Wo = (const float*)d_in[4];
    const float* bo = (const float*)d_in[5];
    float* out = (float*)d_out;

    const int B = in_sizes[0] / D_IN;                  // 8192 states, one per wave
    const int spb = BLOCK / 64;                        // states per block (4)
    const int blocks = (B + spb - 1) / spb;
    hipLaunchKernelGGL(qnet_kernel, dim3(blocks), dim3(BLOCK), 0, stream,
                       x, Wp, bp, qw, Wo, bo, out, B);
}

// Round 8
// 145.912 us; speedup vs baseline: 1.0109x; 1.0109x over previous
//
#include <hip/hip_runtime.h>

#define NQ      10
#define NLAYERS 4
#define D_IN    784
#define BLOCK   256   // 4 waves per workgroup, ONE state per wave, amp-pair pk packing.
// R20: fit the register appetite to a 5-wave budget. R19's (6,8) probe: occupancy DID
// rise 34.5->45.7% (waves_per_eu min is the residency lever) but spilled 45MB -> true
// appetite ~120-130 regs (32 state + ~32 hoisted diag tables + ~25 wave-uniform scalar
// coefficients + temps). Fix: (a) waves_per_eu(5,8) = 102-reg budget, 5 waves/SIMD;
// (b) SGPR-hoist the wave-uniform scalars (per-layer RY cos/sin x20, diag half-angles x6)
// via v_readfirstlane -- they are wave-invariant, VOP3P reads 1 SGPR(-pair)/instr, so
// they cost 0 VGPRs held live across the layer body. Appetite est. ~85-95 < 102.
// (readfirstlane on full-exec uniform LDS loads; unrelated to R8's locked divergent
// readlane reductions.)
// Outcomes: clean (WRITE ~320KB) -> occ 50-60, busy 78-85, dur 65-70us. Spill again ->
// revert knob to (2,8) keeping diet; attack stream length next.
// R18 (kept): layer factorization Rot = D_omega * RY * D_phi; diagonals as lane-phase
// sincos x 16-entry LDS table; last D_omega skipped; embedding = product-state init;
// ring CNOT(9,0) folded into D_phi signs / ry0_fused / measurement masks.
// Tripwire: WRITE_SIZE ~0.3 MB. absmax must stay ~0.004.
// LOCKED: reductions use plain __shfl_xor only (R8 DPP reductions diverged across graph
// replays). DPP confined to full-exec lane exchanges (stable since R4).

// Amplitude index i (10 bits): lane bits 9..4 (q0..q5 = lane&32..lane&1),
// array-index bits 3..1 (q6,q7,q8 = a&4,a&2,a&1), component bit 0 (q9 = f2 comp).

typedef __attribute__((ext_vector_type(2))) float f2;

__device__ __forceinline__ f2 sp(float v) { f2 r; r.x = v; r.y = v; return r; }
__device__ __forceinline__ f2 swapc(f2 v) { return __builtin_shufflevector(v, v, 1, 0); }

// wave-uniform value -> SGPR (frees a VGPR for the whole live range)
__device__ __forceinline__ float rfl(float v) {
    return __int_as_float(__builtin_amdgcn_readfirstlane(__float_as_int(v)));
}

// ---- lane exchange: xor LB, VALU pipe where possible ----
template<int LB>
__device__ __forceinline__ float lx(float v) {
    if constexpr (LB == 1) {        // quad_perm [1,0,3,2]
        return __int_as_float(__builtin_amdgcn_update_dpp(
            0, __float_as_int(v), 0xB1, 0xF, 0xF, false));
    } else if constexpr (LB == 2) { // quad_perm [2,3,0,1]
        return __int_as_float(__builtin_amdgcn_update_dpp(
            0, __float_as_int(v), 0x4E, 0xF, 0xF, false));
    } else if constexpr (LB == 8) { // row_ror:8 within 16 == xor 8 (VALU)
        return __int_as_float(__builtin_amdgcn_update_dpp(
            0, __float_as_int(v), 0x128, 0xF, 0xF, false));
    } else {
        return __shfl_xor(v, LB, 64);   // LB==4: DS pipe (no VALU equivalent)
    }
}

template<int LB>
__device__ __forceinline__ f2 lx2(f2 v) {
    f2 r; r.x = lx<LB>(v.x); r.y = lx<LB>(v.y); return r;
}

// ---- permlane pair swap (VALU pipe) ----
template<int HALF>
__device__ __forceinline__ void plswap(f2 &d, f2 &s) {
    if constexpr (HALF == 32) {
        auto rx = __builtin_amdgcn_permlane32_swap(__float_as_int(d.x), __float_as_int(s.x), false, false);
        auto ry = __builtin_amdgcn_permlane32_swap(__float_as_int(d.y), __float_as_int(s.y), false, false);
        d.x = __int_as_float(rx[0]); s.x = __int_as_float(rx[1]);
        d.y = __int_as_float(ry[0]); s.y = __int_as_float(ry[1]);
    } else {
        auto rx = __builtin_amdgcn_permlane16_swap(__float_as_int(d.x), __float_as_int(s.x), false, false);
        auto ry = __builtin_amdgcn_permlane16_swap(__float_as_int(d.y), __float_as_int(s.y), false, false);
        d.x = __int_as_float(rx[0]); s.x = __int_as_float(rx[1]);
        d.y = __int_as_float(ry[0]); s.y = __int_as_float(ry[1]);
    }
}

// ---- real RY on lane bit 32/16 via permlane pair-processing ----
template<int HALF>
__device__ __forceinline__ void ry_pl(f2 (&re)[8], f2 (&im)[8], float c, float s) {
#pragma unroll
    for (int a = 0; a < 8; a += 2) {
        f2 ur = re[a], vr = re[a + 1], ui = im[a], vi = im[a + 1];
        plswap<HALF>(ur, vr); plswap<HALF>(ui, vi);
        f2 nur = sp(c)*ur - sp(s)*vr;   f2 nui = sp(c)*ui - sp(s)*vi;
        f2 nvr = sp(s)*ur + sp(c)*vr;   f2 nvi = sp(s)*ui + sp(c)*vi;
        plswap<HALF>(nur, nvr); plswap<HALF>(nui, nvi);
        re[a] = nur; re[a + 1] = nvr; im[a] = nui; im[a + 1] = nvi;
    }
}

// ---- real RY on q0 (lane bit 32) with pending CNOT(ctrl=comp, tgt=bit32) consumed. ----
__device__ __forceinline__ void ry0_fused(f2 (&re)[8], f2 (&im)[8], float c, float s) {
    f2 K1, K2, K3, K4;
    K1.x =  c; K1.y = -s;   K2.x = -s; K2.y =  c;
    K3.x =  s; K3.y =  c;   K4.x =  c; K4.y =  s;
#pragma unroll
    for (int a = 0; a < 8; a += 2) {
        f2 ur = re[a], vr = re[a + 1], ui = im[a], vi = im[a + 1];
        plswap<32>(ur, vr); plswap<32>(ui, vi);
        f2 nur = K1*ur + K2*vr;   f2 nui = K1*ui + K2*vi;
        f2 nvr = K3*ur + K4*vr;   f2 nvi = K3*ui + K4*vi;
        plswap<32>(nur, nvr); plswap<32>(nui, nvi);
        re[a] = nur; re[a + 1] = nvr; im[a] = nui; im[a + 1] = nvi;
    }
}

// ---- real RY on lane bit LB (8,4,2,1): exchange + 4 pk per reg ----
template<int LB>
__device__ __forceinline__ void ry_lane(f2 (&re)[8], f2 (&im)[8], int lane, float c, float s) {
    const float o = (lane & LB) ? s : -s;   // lo: u' = c*u - s*v ; hi: v' = c*v + s*u
#pragma unroll
    for (int a = 0; a < 8; a++) {
        f2 ore = lx2<LB>(re[a]);
        f2 oim = lx2<LB>(im[a]);
        re[a] = sp(c)*re[a] + sp(o)*ore;
        im[a] = sp(c)*im[a] + sp(o)*oim;
    }
}

// ---- real RY on array-index bit MB (4,2,1): 8 pk per pair ----
template<int MB>
__device__ __forceinline__ void ry_reg(f2 (&re)[8], f2 (&im)[8], float c, float s) {
#pragma unroll
    for (int a = 0; a < 8; a++) {
        if (!(a & MB)) {
            const int a1 = a | MB;
            f2 r0 = re[a], r1 = re[a1], i0 = im[a], i1 = im[a1];
            re[a]  = sp(c)*r0 - sp(s)*r1;   re[a1] = sp(s)*r0 + sp(c)*r1;
            im[a]  = sp(c)*i0 - sp(s)*i1;   im[a1] = sp(s)*i0 + sp(c)*i1;
        }
    }
}

// ---- real RY on the component bit (q9): swapc + 4 pk per reg ----
__device__ __forceinline__ void ry_comp(f2 (&re)[8], f2 (&im)[8], float c, float s) {
    f2 Ks; Ks.x = -s; Ks.y = s;
#pragma unroll
    for (int a = 0; a < 8; a++) {
        f2 sre = swapc(re[a]), sim = swapc(im[a]);
        re[a] = sp(c)*re[a] + Ks*sre;
        im[a] = sp(c)*im[a] + Ks*sim;
    }
}

// ---- diagonal apply: per-amp factor = e^{i*lane_phase} * e^{i*reg_phase[a]}.
// XOR0: pending CNOT(q9->q0) folded in -> phi0 lane-term sign flips on component.
// lz values are wave-uniform -> pulled through rfl() into SGPRs. ----
template<bool XOR0>
__device__ __forceinline__ void diag_apply(f2 (&re)[8], f2 (&im)[8], int lane,
                                           const float* lz, const f2* DC, const f2* DS) {
    const float z0 = rfl(lz[0]), z1 = rfl(lz[1]), z2 = rfl(lz[2]);
    const float z3 = rfl(lz[3]), z4 = rfl(lz[4]), z5 = rfl(lz[5]);
    float lp = 0.f;
    lp += (lane & 16) ? z1 : -z1;
    lp += (lane &  8) ? z2 : -z2;
    lp += (lane &  4) ? z3 : -z3;
    lp += (lane &  2) ? z4 : -z4;
    lp += (lane &  1) ? z5 : -z5;
    const float t0 = (lane & 32) ? z0 : -z0;
    f2 cl, sl;
    if constexpr (XOR0) {
        float sa, ca, sb, cb;
        sincosf(lp + t0, &sa, &ca);
        sincosf(lp - t0, &sb, &cb);
        cl.x = ca; cl.y = cb; sl.x = sa; sl.y = sb;
    } else {
        float sa, ca;
        sincosf(lp + t0, &sa, &ca);
        cl = sp(ca); sl = sp(sa);
    }
#pragma unroll
    for (int a = 0; a < 8; a++) {
        f2 cr = cl*DC[a] - sl*DS[a];      // combined complex coefficient
        f2 ci = cl*DS[a] + sl*DC[a];
        f2 nr = cr*re[a] - ci*im[a];
        f2 ni = cr*im[a] + ci*re[a];
        re[a] = nr; im[a] = ni;
    }
}

__device__ __forceinline__ void swapf2(f2 &a, f2 &b) { f2 t = a; a = b; b = t; }

// ---- CNOT ring: Gray bpermute (q0..q5 chain), (5,6) cndmask, renames, (8,9) comp swap.
// (9,0) NOT applied: folded into next layer's D_phi/ry0_fused or measurement signs. ----
__device__ __forceinline__ void ring(f2 (&re)[8], f2 (&im)[8], int lane, int bidx) {
#pragma unroll
    for (int a = 0; a < 8; a++) {
        re[a].x = __int_as_float(__builtin_amdgcn_ds_bpermute(bidx, __float_as_int(re[a].x)));
        re[a].y = __int_as_float(__builtin_amdgcn_ds_bpermute(bidx, __float_as_int(re[a].y)));
        im[a].x = __int_as_float(__builtin_amdgcn_ds_bpermute(bidx, __float_as_int(im[a].x)));
        im[a].y = __int_as_float(__builtin_amdgcn_ds_bpermute(bidx, __float_as_int(im[a].y)));
    }
    const bool ctl = (lane & 1) != 0;      // (5,6): ctrl lane bit0, tgt array bit 4
#pragma unroll
    for (int a = 0; a < 4; a++) {
        f2 A0 = re[a], A1 = re[a + 4], B0 = im[a], B1 = im[a + 4];
        f2 n0, n1, m0, m1;
        n0.x = ctl ? A1.x : A0.x;  n0.y = ctl ? A1.y : A0.y;
        n1.x = ctl ? A0.x : A1.x;  n1.y = ctl ? A0.y : A1.y;
        m0.x = ctl ? B1.x : B0.x;  m0.y = ctl ? B1.y : B0.y;
        m1.x = ctl ? B0.x : B1.x;  m1.y = ctl ? B0.y : B1.y;
        re[a] = n0; re[a + 4] = n1; im[a] = m0; im[a + 4] = m1;
    }
    // (6,7): ctrl array bit 4, tgt bit 2: free renames
    swapf2(re[4], re[6]); swapf2(re[5], re[7]); swapf2(im[4], im[6]); swapf2(im[5], im[7]);
    // (7,8): ctrl array bit 2, tgt bit 1
    swapf2(re[2], re[3]); swapf2(re[6], re[7]); swapf2(im[2], im[3]); swapf2(im[6], im[7]);
    // (8,9): ctrl array bit 1, tgt component
#pragma unroll
    for (int a = 1; a < 8; a += 2) { re[a] = swapc(re[a]); im[a] = swapc(im[a]); }
}

__global__ __launch_bounds__(BLOCK)
__attribute__((amdgpu_waves_per_eu(5, 8)))
void qnet_kernel(
    const float* __restrict__ x,
    const float* __restrict__ Wp,
    const float* __restrict__ bp,
    const float* __restrict__ qw,
    const float* __restrict__ Wo,
    const float* __restrict__ bo,
    float* __restrict__ out, int B)
{
    // Per-WG tables:
    __shared__ float ryt[NLAYERS * NQ * 2];        // (l*10+q)*2: cos(th/2), sin(th/2)
    __shared__ float lzt[NLAYERS * 2 * 6];         // (l*2+t)*6+q: half-angles q0..q5 (t:0=phi,1=omega)
    __shared__ __align__(8) f2 dct[NLAYERS * 2 * 8];  // (l*2+t)*8+a: reg-diag cos (comp-packed)
    __shared__ __align__(8) f2 dst[NLAYERS * 2 * 8];  // reg-diag sin

    const int tid  = threadIdx.x;
    const int lane = tid & 63;
    const int s    = blockIdx.x * (BLOCK / 64) + (tid >> 6);   // one state per wave

    if (tid < NLAYERS * NQ) {                      // 40 threads: RY pairs + lane half-angles
        const int l = tid / NQ, q = tid % NQ;
        float th = qw[tid * 3 + 1];
        float sc, cc; sincosf(0.5f * th, &sc, &cc);
        ryt[tid * 2] = cc; ryt[tid * 2 + 1] = sc;
        if (q < 6) {
            lzt[(l * 2 + 0) * 6 + q] = 0.5f * qw[tid * 3 + 0];   // phi
            lzt[(l * 2 + 1) * 6 + q] = 0.5f * qw[tid * 3 + 2];   // omega
        }
    }
    if (tid >= 64 && tid < 128) {                  // 64 threads: reg-diag tables
        const int idx = tid - 64;
        const int l = idx >> 4, t = (idx >> 3) & 1, a = idx & 7;
        const float* ql = qw + (size_t)l * NQ * 3;
        const int off = t ? 2 : 0;
        const float p6 = 0.5f * ql[6 * 3 + off], p7 = 0.5f * ql[7 * 3 + off];
        const float p8 = 0.5f * ql[8 * 3 + off], p9 = 0.5f * ql[9 * 3 + off];
        const float base = ((a & 4) ? p6 : -p6) + ((a & 2) ? p7 : -p7) + ((a & 1) ? p8 : -p8);
        float s0, c0, s1, c1;
        sincosf(base - p9, &s0, &c0);              // comp 0: q9 bit = 0
        sincosf(base + p9, &s1, &c1);              // comp 1: q9 bit = 1
        f2 dc; dc.x = c0; dc.y = c1;
        f2 ds; ds.x = s0; ds.y = s1;
        dct[(l * 2 + t) * 8 + a] = dc;
        dst[(l * 2 + t) * 8 + a] = ds;
    }
    __syncthreads();
    if (s >= B) return;

    // ---- projection (float4: 784 = 3*256 + 16) ----
    float acc[NQ];
#pragma unroll
    for (int q = 0; q < NQ; q++) acc[q] = 0.f;
    const float* xr = x + (size_t)s * D_IN;
#pragma unroll
    for (int it = 0; it < 3; it++) {
        const int d = (it * 64 + lane) * 4;
        float4 xv = *(const float4*)(xr + d);
#pragma unroll
        for (int q = 0; q < NQ; q++) {
            float4 wv = *(const float4*)(Wp + q * D_IN + d);
            acc[q] += xv.x * wv.x + xv.y * wv.y + xv.z * wv.z + xv.w * wv.w;
        }
    }
    if (lane < 4) {                                // tail 768..783
        const int d = (192 + lane) * 4;
        float4 xv = *(const float4*)(xr + d);
#pragma unroll
        for (int q = 0; q < NQ; q++) {
            float4 wv = *(const float4*)(Wp + q * D_IN + d);
            acc[q] += xv.x * wv.x + xv.y * wv.y + xv.z * wv.z + xv.w * wv.w;
        }
    }
#pragma unroll
    for (int q = 0; q < NQ; q++) {
#pragma unroll
        for (int o = 1; o < 64; o <<= 1) acc[q] += __shfl_xor(acc[q], o, 64);
    }
    float myc = 1.f, mys = 0.f;
    if (lane < NQ) {
        float h = tanhf(acc[lane] + bp[lane]);
        sincosf(0.5f * h, &mys, &myc);
    }

    // ---- embedding: direct product-state init (all-real, separable) ----
    f2 re[8], im[8];
    float lf = 1.f;
    {
        float cq, sq;
#define SEL(Q, MASK) cq = __shfl(myc, Q, 64); sq = __shfl(mys, Q, 64); \
                     lf *= (lane & MASK) ? sq : cq;
        SEL(0, 32) SEL(1, 16) SEL(2, 8) SEL(3, 4) SEL(4, 2) SEL(5, 1)
#undef SEL
        const float c6 = __shfl(myc, 6, 64), s6 = __shfl(mys, 6, 64);
        const float c7 = __shfl(myc, 7, 64), s7 = __shfl(mys, 7, 64);
        const float c8 = __shfl(myc, 8, 64), s8 = __shfl(mys, 8, 64);
        const float c9 = __shfl(myc, 9, 64), s9 = __shfl(mys, 9, 64);
#pragma unroll
        for (int a = 0; a < 8; a++) {
            float t = ((a & 4) ? s6 : c6) * ((a & 2) ? s7 : c7) * ((a & 1) ? s8 : c8) * lf;
            re[a].x = t * c9; re[a].y = t * s9;
            im[a] = sp(0.f);
        }
    }

    const int bidx = (lane ^ (lane >> 1)) << 2;    // Gray pull for lane CNOT chain

    // ---- layer 0: D_phi, 10 RYs, D_omega, ring ----
    {
        const float* rl = ryt;
        diag_apply<false>(re, im, lane, lzt, dct, dst);                    // D_phi(0)
        ry_pl<32>(re, im, rfl(rl[0]), rfl(rl[1]));
        ry_pl<16>(re, im, rfl(rl[2]), rfl(rl[3]));
        ry_lane<8>(re, im, lane, rfl(rl[4]), rfl(rl[5]));
        ry_lane<4>(re, im, lane, rfl(rl[6]), rfl(rl[7]));
        ry_lane<2>(re, im, lane, rfl(rl[8]), rfl(rl[9]));
        ry_lane<1>(re, im, lane, rfl(rl[10]), rfl(rl[11]));
        ry_reg<4>(re, im, rfl(rl[12]), rfl(rl[13]));
        ry_reg<2>(re, im, rfl(rl[14]), rfl(rl[15]));
        ry_reg<1>(re, im, rfl(rl[16]), rfl(rl[17]));
        ry_comp(re, im, rfl(rl[18]), rfl(rl[19]));
        diag_apply<false>(re, im, lane, lzt + 6, dct + 8, dst + 8);        // D_omega(0)
        ring(re, im, lane, bidx);                  // leaves (9,0) pending
    }

    // ---- layers 1..3 ----
    for (int l = 1; l < NLAYERS; l++) {
        const float* rl = ryt + l * NQ * 2;
        diag_apply<true>(re, im, lane, lzt + (l * 2) * 6,
                         dct + (l * 2) * 8, dst + (l * 2) * 8);            // D'_phi (C folded)
        ry0_fused(re, im, rfl(rl[0]), rfl(rl[1]));  // consumes pending C
        ry_pl<16>(re, im, rfl(rl[2]), rfl(rl[3]));
        ry_lane<8>(re, im, lane, rfl(rl[4]), rfl(rl[5]));
        ry_lane<4>(re, im, lane, rfl(rl[6]), rfl(rl[7]));
        ry_lane<2>(re, im, lane, rfl(rl[8]), rfl(rl[9]));
        ry_lane<1>(re, im, lane, rfl(rl[10]), rfl(rl[11]));
        ry_reg<4>(re, im, rfl(rl[12]), rfl(rl[13]));
        ry_reg<2>(re, im, rfl(rl[14]), rfl(rl[15]));
        ry_reg<1>(re, im, rfl(rl[16]), rfl(rl[17]));
        ry_comp(re, im, rfl(rl[18]), rfl(rl[19]));
        if (l < NLAYERS - 1)                       // last D_omega skipped (|amp|^2 invariant)
            diag_apply<false>(re, im, lane, lzt + (l * 2 + 1) * 6,
                              dct + (l * 2 + 1) * 8, dst + (l * 2 + 1) * 8);
        ring(re, im, lane, bidx);                  // (9,0) pending again
    }
    // Final pending (9,0) CNOT folded into measurement sign masks below.

    // ---- measurement: Z expectation per qubit ----
    f2 S2 = {0.f, 0.f}, z62 = {0.f, 0.f}, z72 = {0.f, 0.f}, z82 = {0.f, 0.f};
#pragma unroll
    for (int a = 0; a < 8; a++) {
        f2 p = re[a] * re[a] + im[a] * im[a];
        S2 += p;
        if (a & 4) z62 -= p; else z62 += p;
        if (a & 2) z72 -= p; else z72 += p;
        if (a & 1) z82 -= p; else z82 += p;
    }
    const float Ssum = S2.x + S2.y;
    const float Sdif = S2.x - S2.y;
    float zq[NQ];
    zq[0] = (lane & 32) ? -Sdif : Sdif;   // q0: lane bit32 XOR component (folded CNOT)
    zq[1] = (lane & 16) ? -Ssum : Ssum;
    zq[2] = (lane &  8) ? -Ssum : Ssum;
    zq[3] = (lane &  4) ? -Ssum : Ssum;
    zq[4] = (lane &  2) ? -Ssum : Ssum;
    zq[5] = (lane &  1) ? -Ssum : Ssum;
    zq[6] = z62.x + z62.y;
    zq[7] = z72.x + z72.y;
    zq[8] = z82.x + z82.y;
    zq[9] = Sdif;                          // q9: component bit (untouched by folded CNOT)
#pragma unroll
    for (int q = 0; q < NQ; q++) {
#pragma unroll
        for (int o = 1; o < 64; o <<= 1) zq[q] += __shfl_xor(zq[q], o, 64);
    }

    // ---- output projection: out = zq @ Wo^T + bo ----
    if (lane < NQ) {
        const float* wrow = Wo + lane * NQ;
        float o0 = bo[lane];
#pragma unroll
        for (int q = 0; q < NQ; q++) o0 += zq[q] * wrow[q];
        out[(size_t)s * NQ + lane] = o0;
    }
}

extern "C" void kernel_launch(void* const* d_in, const int* in_sizes, int n_in,
                              void* d_out, int out_size, void* d_ws, size_t ws_size,
                              hipStream_t stream) {
    const float* x  = (const float*)d_in[0];
    const float* Wp = (const float*)d_in[1];
    const float* bp = (const float*)d_in[2];
    const float* qw = (const float*)d_in[3];
    const float* Wo = (const float*)d_in[4];
    const float* bo = (const float*)d_in[5];
    float* out = (float*)d_out;

    const int B = in_sizes[0] / D_IN;                  // 8192 states, one per wave
    const int spb = BLOCK / 64;                        // states per block (4)
    const int blocks = (B + spb - 1) / spb;
    hipLaunchKernelGGL(qnet_kernel, dim3(blocks), dim3(BLOCK), 0, stream,
                       x, Wp, bp, qw, Wo, bo, out, B);
}